// Round 1
// baseline (234.962 us; speedup 1.0000x reference)
//
#include <hip/hip_runtime.h>

// Problem constants (fixed by reference)
constexpr int N_AG = 4096;   // N agents
constexpr int M_CL = 256;    // M clusters
constexpr int KD   = 32;     // K dim
constexpr float WEPS = 1e-6f;

// ws layout (floats)
constexpr int PART_STRIDE = 1088;                 // [S2(1024) | S1(32) | Z | count | pad]
constexpr int PART_SZ = M_CL * 4 * PART_STRIDE;   // 1,114,112
constexpr int VT_OFF  = PART_SZ;                  // vT (32 x 4096) k-major
constexpr int WT_OFF  = VT_OFF + N_AG * KD;       // Wt (256 x 4096) masked
constexpr int CNT_OFF = WT_OFF + N_AG * M_CL;     // 256 u32 completion counters
// total ~2.29M floats = 9.2 MB

typedef __attribute__((ext_vector_type(8))) short short8;   // 8 bf16 (4 VGPRs)
typedef __attribute__((ext_vector_type(4))) float f32x4;

__device__ __forceinline__ float rlane(float x, int l) {
    return __int_as_float(__builtin_amdgcn_readlane(__float_as_int(x), l));
}

// ---------------------------------------------------------------------------
// GJ: template-recursive Gauss-Jordan, J compile-time so col[] stays in regs
// (R6 lesson: #pragma unroll silently failed -> scratch -> 50us vs 7us).
// ---------------------------------------------------------------------------
template<int J>
struct GJ {
    static __device__ __forceinline__ void run(float (&col)[32]) {
        const float piv  = rlane(col[J], J);
        const float pinv = 1.0f / piv;
        col[J] *= pinv;
        #pragma unroll
        for (int i = 0; i < 32; ++i) {
            if (i == J) continue;
            const float fi = rlane(col[i], J);
            col[i] = fmaf(-fi, col[J], col[i]);
        }
        GJ<J + 1>::run(col);
    }
};
template<> struct GJ<32> {
    static __device__ __forceinline__ void run(float (&)[32]) {}
};

// ---------------------------------------------------------------------------
// K1 prep (role-split, ROUND-7): removes the solve->transpose serialization.
//  blocks 0..1023:    masked W (4096x256) -> Wt (256x4096)   [independent of solve]
//  blocks 1024..2047: 32x32 SPD solve (4 matrices/block, 1 wave each), then
//                     in-block LDS transpose -> write vT (32x4096) directly.
//                     v intermediate eliminated. Block 1024 also zeroes the
//                     per-m completion counters used by the fused combine.
// ---------------------------------------------------------------------------
__global__ __launch_bounds__(256) void prep_kernel(const float* __restrict__ W,
                                                   const float* __restrict__ mu,
                                                   const float* __restrict__ oc,
                                                   float* __restrict__ ws) {
    __shared__ float tb[32][33];
    __shared__ float sv[4][32];
    const int bid = blockIdx.x;
    const int t   = threadIdx.x;

    if (bid < 1024) {
        // ---- masked W transpose tile ----
        const int x = t & 31;
        const int y = t >> 5;                 // 0..7
        const int n0 = (bid & 127) * 32;
        const int m0 = (bid >> 7) * 32;
        float* Wt = ws + WT_OFF;
        #pragma unroll
        for (int r = 0; r < 4; ++r) {
            const int n = y + 8 * r;
            float w = W[(size_t)(n0 + n) * 256 + m0 + x];
            tb[n][x] = (w >= WEPS) ? w : 0.0f;
        }
        __syncthreads();
        #pragma unroll
        for (int r = 0; r < 4; ++r) {
            const int mm = y + 8 * r;
            Wt[(size_t)(m0 + mm) * 4096 + n0 + x] = tb[x][mm];
        }
    } else {
        if (bid == 1024) {
            reinterpret_cast<unsigned*>(ws + CNT_OFF)[t & 255] = 0u;
        }
        // ---- batched solve: wave w owns matrix n0+w; lane c owns column c ----
        const int lane = t & 63;
        const int wid  = t >> 6;
        const int n0   = (bid - 1024) * 4;
        const int idx  = n0 + wid;
        const int c = (lane < 32) ? lane : 32;

        float col[32];
        #pragma unroll
        for (int i = 0; i < 32; ++i) {
            col[i] = (c < 32) ? oc[(size_t)idx * 1024 + i * 32 + c]
                              : mu[(size_t)idx * 32 + i];
        }
        GJ<0>::run(col);

        float res = 0.0f;
        #pragma unroll
        for (int i = 0; i < 32; ++i) {
            const float xi = rlane(col[i], 32);
            if (lane == i) res = xi;
        }
        if (lane < 32) sv[wid][lane] = res;
        __syncthreads();
        // vT[k][n0..n0+3]: 16B-coalesced per k-row
        if (t < 128) {
            const int k = t >> 2;
            const int j = t & 3;
            ws[VT_OFF + (size_t)k * 4096 + n0 + j] = sv[j][k];
        }
    }
}

// ---------------------------------------------------------------------------
// K2 (MFMA partial + fused combine, ROUND-7): per (m,p) block (p = quarter of
// n), compute S2 = sum_n w v v^T via u = sqrt(w) v, S2 = u^T u (MFMA).
// u split hi/lo bf16 (RTZ): S2 ~= Uh^T Uh + (Uh^T Ul) + (Uh^T Ul)^T.
// Each of 4 waves owns 256 n's (wave-private LDS, zero barriers in main loop).
// NEW: last-done block per m (device-scope atomicAdd on counter, threadfence
// release/acquire) runs the combine in-place:
//   G = op^T op ; psi = tr(G S2)/Z - vbar^T G vbar ; gate count>=2
// ---------------------------------------------------------------------------
__global__ __launch_bounds__(256, 3) void partial_kernel(const float* __restrict__ Wt,
                                                         const float* __restrict__ vT,
                                                         float* __restrict__ wsout,
                                                         const float* __restrict__ op,
                                                         unsigned* __restrict__ cnt,
                                                         float* __restrict__ out) {
    const int m = blockIdx.x >> 2;
    const int p = blockIdx.x & 3;
    const int t = threadIdx.x;
    const int lane = t & 63;
    const int wv   = t >> 6;     // wave id 0..3

    __shared__ unsigned ubuf[4][2][32 * 36];  // [wave][hi/lo][k*36 + n/2] : 36,864 B
    __shared__ float swbuf[1024];             // sqrt(w) for this (m,p)
    __shared__ float zred[256];
    __shared__ float s1buf[32];
    __shared__ unsigned lastf;

    // ---- stage w: sqrt, Z, count ----
    const float4 wv4 = reinterpret_cast<const float4*>(Wt + (size_t)m * 4096 + p * 1024)[t];
    float zacc = wv4.x + wv4.y + wv4.z + wv4.w;
    float cacc = (wv4.x >= WEPS ? 1.f : 0.f) + (wv4.y >= WEPS ? 1.f : 0.f)
               + (wv4.z >= WEPS ? 1.f : 0.f) + (wv4.w >= WEPS ? 1.f : 0.f);
    reinterpret_cast<float4*>(swbuf)[t] =
        make_float4(sqrtf(wv4.x), sqrtf(wv4.y), sqrtf(wv4.z), sqrtf(wv4.w));
    if (t < 32) s1buf[t] = 0.0f;
    __syncthreads();

    f32x4 Chh[4], Chl[4];
    #pragma unroll
    for (int q = 0; q < 4; ++q) {
        Chh[q] = (f32x4){0.f, 0.f, 0.f, 0.f};
        Chl[q] = (f32x4){0.f, 0.f, 0.f, 0.f};
    }
    float s1acc[4] = {0.f, 0.f, 0.f, 0.f};

    const int krow = lane >> 3;        // 0..7
    const int nsub = (lane & 7) * 4;   // 0..28

    for (int rnd = 0; rnd < 4; ++rnd) {
        const int nloc0 = wv * 256 + rnd * 64;   // block-local n base of this wave-round

        // ---- conversion: 64 n x 32 k, fp32 -> u -> bf16 hi/lo in LDS ----
        #pragma unroll
        for (int it = 0; it < 8; ++it) {
            const int k  = krow + 8 * (it & 3);
            const int nn = nsub + 32 * (it >> 2);
            const float4 v4 = *reinterpret_cast<const float4*>(
                vT + (size_t)k * 4096 + p * 1024 + nloc0 + nn);
            const float4 s4 = *reinterpret_cast<const float4*>(&swbuf[nloc0 + nn]);
            const float ux = v4.x * s4.x, uy = v4.y * s4.y;
            const float uz = v4.z * s4.z, uw = v4.w * s4.w;
            const unsigned bx = __float_as_uint(ux), by = __float_as_uint(uy);
            const unsigned bz = __float_as_uint(uz), bw = __float_as_uint(uw);
            const unsigned hi01 = __builtin_amdgcn_perm(by, bx, 0x07060302u);
            const unsigned hi23 = __builtin_amdgcn_perm(bw, bz, 0x07060302u);
            const float lx = ux - __uint_as_float(bx & 0xFFFF0000u);
            const float ly = uy - __uint_as_float(by & 0xFFFF0000u);
            const float lz = uz - __uint_as_float(bz & 0xFFFF0000u);
            const float lw = uw - __uint_as_float(bw & 0xFFFF0000u);
            const unsigned lo01 = __builtin_amdgcn_perm(__float_as_uint(ly), __float_as_uint(lx), 0x07060302u);
            const unsigned lo23 = __builtin_amdgcn_perm(__float_as_uint(lw), __float_as_uint(lz), 0x07060302u);
            const int dwi = k * 36 + (nn >> 1);
            *reinterpret_cast<uint2*>(&ubuf[wv][0][dwi]) = make_uint2(hi01, hi23);
            *reinterpret_cast<uint2*>(&ubuf[wv][1][dwi]) = make_uint2(lo01, lo23);
            // S1 += w*v = sw*u
            s1acc[it & 3] += ux * s4.x + uy * s4.y + uz * s4.z + uw * s4.w;
        }

        // ---- MFMA: 2 chunks of 32 n ----
        #pragma unroll
        for (int c2 = 0; c2 < 2; ++c2) {
            const int ndw = (c2 * 32 + (lane >> 4) * 8) >> 1;
            const int r0 = (lane & 15) * 36 + ndw;
            const int r1 = r0 + 16 * 36;
            const short8 h0 = *reinterpret_cast<const short8*>(&ubuf[wv][0][r0]);
            const short8 h1 = *reinterpret_cast<const short8*>(&ubuf[wv][0][r1]);
            const short8 l0 = *reinterpret_cast<const short8*>(&ubuf[wv][1][r0]);
            const short8 l1 = *reinterpret_cast<const short8*>(&ubuf[wv][1][r1]);
            Chh[0] = __builtin_amdgcn_mfma_f32_16x16x32_bf16(h0, h0, Chh[0], 0, 0, 0);
            Chh[1] = __builtin_amdgcn_mfma_f32_16x16x32_bf16(h0, h1, Chh[1], 0, 0, 0);
            Chh[2] = __builtin_amdgcn_mfma_f32_16x16x32_bf16(h1, h0, Chh[2], 0, 0, 0);
            Chh[3] = __builtin_amdgcn_mfma_f32_16x16x32_bf16(h1, h1, Chh[3], 0, 0, 0);
            Chl[0] = __builtin_amdgcn_mfma_f32_16x16x32_bf16(h0, l0, Chl[0], 0, 0, 0);
            Chl[1] = __builtin_amdgcn_mfma_f32_16x16x32_bf16(h0, l1, Chl[1], 0, 0, 0);
            Chl[2] = __builtin_amdgcn_mfma_f32_16x16x32_bf16(h1, l0, Chl[2], 0, 0, 0);
            Chl[3] = __builtin_amdgcn_mfma_f32_16x16x32_bf16(h1, l1, Chl[3], 0, 0, 0);
        }
    }

    // ---- S1 reduce: 8 consecutive lanes share k ----
    #pragma unroll
    for (int j = 0; j < 4; ++j) {
        float r = s1acc[j];
        r += __shfl_xor(r, 1);
        r += __shfl_xor(r, 2);
        r += __shfl_xor(r, 4);
        if ((lane & 7) == 0) atomicAdd(&s1buf[krow + 8 * j], r);
    }
    __syncthreads();

    // ---- epilogue: scatter quadrants to wave-private LDS, add D^T ----
    float* redw = reinterpret_cast<float*>(&ubuf[wv][0][0]);  // 1024 of 1152 dw
    #pragma unroll
    for (int q = 0; q < 4; ++q) {
        const int I = q >> 1, J = q & 1;
        #pragma unroll
        for (int r = 0; r < 4; ++r) {
            const int a = I * 16 + (lane >> 4) * 4 + r;
            const int b = J * 16 + (lane & 15);
            redw[a * 32 + b] = Chh[q][r] + Chl[q][r];
        }
    }
    __syncthreads();
    #pragma unroll
    for (int q = 0; q < 4; ++q) {
        const int I = q >> 1, J = q & 1;
        #pragma unroll
        for (int r = 0; r < 4; ++r) {
            const int a = I * 16 + (lane >> 4) * 4 + r;
            const int b = J * 16 + (lane & 15);
            redw[b * 32 + a] += Chl[q][r];
        }
    }
    __syncthreads();

    // ---- cross-wave sum + write record ----
    const size_t base = (size_t)(m * 4 + p) * PART_STRIDE;
    float o0 = 0.f, o1 = 0.f, o2 = 0.f, o3 = 0.f;
    #pragma unroll
    for (int ww = 0; ww < 4; ++ww) {
        const float4 x = *reinterpret_cast<const float4*>(
            &reinterpret_cast<float*>(&ubuf[ww][0][0])[t * 4]);
        o0 += x.x; o1 += x.y; o2 += x.z; o3 += x.w;
    }
    *reinterpret_cast<float4*>(&wsout[base + t * 4]) = make_float4(o0, o1, o2, o3);

    // ---- Z / count reductions ----
    zred[t] = zacc; __syncthreads();
    #pragma unroll
    for (int s = 128; s > 0; s >>= 1) {
        if (t < s) zred[t] += zred[t + s];
        __syncthreads();
    }
    if (t == 0) wsout[base + 1056] = zred[0];
    __syncthreads();
    zred[t] = cacc; __syncthreads();
    #pragma unroll
    for (int s = 128; s > 0; s >>= 1) {
        if (t < s) zred[t] += zred[t + s];
        __syncthreads();
    }
    if (t == 0) wsout[base + 1057] = zred[0];
    if (t < 32) wsout[base + 1024 + t] = s1buf[t];

    // ---- fused combine: last of the 4 (m,p) blocks does the reduction ----
    __syncthreads();
    __threadfence();                                 // release: record visible device-wide
    if (t == 0) lastf = atomicAdd(cnt + m, 1u);
    __syncthreads();
    if (lastf != 3u) return;
    __threadfence();                                 // acquire: see other blocks' records

    float* omg = reinterpret_cast<float*>(&ubuf[0][0][0]);   // 32*33 floats, reuse LDS
    #pragma unroll
    for (int i = 0; i < 4; ++i) {
        const int g = t + 256 * i;
        omg[(g >> 5) * 33 + (g & 31)] = op[(size_t)m * 1024 + g];
    }
    const size_t mb = (size_t)m * 4 * PART_STRIDE;
    float Zt = 0.0f, ct = 0.0f, s1 = 0.0f;
    float s2[4] = {0.f, 0.f, 0.f, 0.f};
    #pragma unroll
    for (int p2 = 0; p2 < 4; ++p2) {
        const size_t bp = mb + (size_t)p2 * PART_STRIDE;
        Zt += wsout[bp + 1056];
        ct += wsout[bp + 1057];
        if (t < 32) s1 += wsout[bp + 1024 + t];
        const float4 sp = *reinterpret_cast<const float4*>(&wsout[bp + t * 4]);
        s2[0] += sp.x; s2[1] += sp.y; s2[2] += sp.z; s2[3] += sp.w;
    }
    const float invZ = 1.0f / fmaxf(Zt, 1e-30f);
    __syncthreads();
    if (t < 32) s1buf[t] = s1 * invZ;                // vbar
    __syncthreads();

    const int k  = t >> 3;
    const int l0 = (t & 7) * 4;
    float G[4] = {0.f, 0.f, 0.f, 0.f};
    #pragma unroll
    for (int i = 0; i < 32; ++i) {
        const float ok = omg[i * 33 + k];
        #pragma unroll
        for (int q = 0; q < 4; ++q) G[q] = fmaf(ok, omg[i * 33 + l0 + q], G[q]);
    }
    const float vk = s1buf[k];
    float val = 0.0f;
    #pragma unroll
    for (int q = 0; q < 4; ++q)
        val += G[q] * (s2[q] * invZ - vk * s1buf[l0 + q]);

    zred[t] = val; __syncthreads();
    #pragma unroll
    for (int s = 128; s > 0; s >>= 1) {
        if (t < s) zred[t] += zred[t + s];
        __syncthreads();
    }
    if (t == 0) out[m] = (ct >= 1.5f) ? zred[0] : 0.0f;
}

// ---------------------------------------------------------------------------
extern "C" void kernel_launch(void* const* d_in, const int* in_sizes, int n_in,
                              void* d_out, int out_size, void* d_ws, size_t ws_size,
                              hipStream_t stream) {
    const float* W  = (const float*)d_in[0];  // (4096, 256)
    const float* mu = (const float*)d_in[1];  // (4096, 32)
    const float* oc = (const float*)d_in[2];  // (4096, 32, 32)
    const float* op = (const float*)d_in[3];  // (256, 32, 32)
    float* out = (float*)d_out;               // (256,)
    float* ws  = (float*)d_ws;

    prep_kernel<<<2048, 256, 0, stream>>>(W, mu, oc, ws);
    partial_kernel<<<1024, 256, 0, stream>>>(ws + WT_OFF, ws + VT_OFF, ws,
                                             op, (unsigned*)(ws + CNT_OFF), out);
}

// Round 2
// 107.443 us; speedup vs baseline: 2.1868x; 2.1868x over previous
//
#include <hip/hip_runtime.h>

// Problem constants (fixed by reference)
constexpr int N_AG = 4096;   // N agents
constexpr int M_CL = 256;    // M clusters
constexpr int KD   = 32;     // K dim
constexpr float WEPS = 1e-6f;

// ws layout (floats)
constexpr int PART_STRIDE = 1088;                 // [P(1024, MFMA-lane layout) | S1(32) | Z | count | pad]
constexpr int PART_SZ = M_CL * 4 * PART_STRIDE;   // 1,114,112
constexpr int VT_OFF  = PART_SZ;                  // vT (32 x 4096) k-major
constexpr int WT_OFF  = VT_OFF + N_AG * KD;       // Wt (256 x 4096) masked

typedef __attribute__((ext_vector_type(8))) short short8;   // 8 bf16 (4 VGPRs)
typedef __attribute__((ext_vector_type(4))) float f32x4;

__device__ __forceinline__ float rlane(float x, int l) {
    return __int_as_float(__builtin_amdgcn_readlane(__float_as_int(x), l));
}

// ---------------------------------------------------------------------------
// GJ: template-recursive Gauss-Jordan, J compile-time so col[] stays in regs
// (R6 lesson: #pragma unroll silently failed -> scratch -> 50us vs 7us).
// ---------------------------------------------------------------------------
template<int J>
struct GJ {
    static __device__ __forceinline__ void run(float (&col)[32]) {
        const float piv  = rlane(col[J], J);
        const float pinv = 1.0f / piv;
        col[J] *= pinv;
        #pragma unroll
        for (int i = 0; i < 32; ++i) {
            if (i == J) continue;
            const float fi = rlane(col[i], J);
            col[i] = fmaf(-fi, col[J], col[i]);
        }
        GJ<J + 1>::run(col);
    }
};
template<> struct GJ<32> {
    static __device__ __forceinline__ void run(float (&)[32]) {}
};

// ---------------------------------------------------------------------------
// K1 prep (ROUND-8: kept from R7 — the merge itself was fine):
//  blocks 0..1023:    masked W (4096x256) -> Wt (256x4096)   [independent of solve]
//  blocks 1024..2047: 32x32 SPD solve (4 matrices/block, 1 wave each), then
//                     in-block LDS transpose -> write vT (32x4096) directly.
// ---------------------------------------------------------------------------
__global__ __launch_bounds__(256) void prep_kernel(const float* __restrict__ W,
                                                   const float* __restrict__ mu,
                                                   const float* __restrict__ oc,
                                                   float* __restrict__ ws) {
    __shared__ float tb[32][33];
    __shared__ float sv[4][32];
    const int bid = blockIdx.x;
    const int t   = threadIdx.x;

    if (bid < 1024) {
        // ---- masked W transpose tile ----
        const int x = t & 31;
        const int y = t >> 5;                 // 0..7
        const int n0 = (bid & 127) * 32;
        const int m0 = (bid >> 7) * 32;
        float* Wt = ws + WT_OFF;
        #pragma unroll
        for (int r = 0; r < 4; ++r) {
            const int n = y + 8 * r;
            float w = W[(size_t)(n0 + n) * 256 + m0 + x];
            tb[n][x] = (w >= WEPS) ? w : 0.0f;
        }
        __syncthreads();
        #pragma unroll
        for (int r = 0; r < 4; ++r) {
            const int mm = y + 8 * r;
            Wt[(size_t)(m0 + mm) * 4096 + n0 + x] = tb[x][mm];
        }
    } else {
        // ---- batched solve: wave w owns matrix n0+w; lane c owns column c ----
        const int lane = t & 63;
        const int wid  = t >> 6;
        const int n0   = (bid - 1024) * 4;
        const int idx  = n0 + wid;
        const int c = (lane < 32) ? lane : 32;

        float col[32];
        #pragma unroll
        for (int i = 0; i < 32; ++i) {
            col[i] = (c < 32) ? oc[(size_t)idx * 1024 + i * 32 + c]
                              : mu[(size_t)idx * 32 + i];
        }
        GJ<0>::run(col);

        float res = 0.0f;
        #pragma unroll
        for (int i = 0; i < 32; ++i) {
            const float xi = rlane(col[i], 32);
            if (lane == i) res = xi;
        }
        if (lane < 32) sv[wid][lane] = res;
        __syncthreads();
        // vT[k][n0..n0+3]: 16B-coalesced per k-row
        if (t < 128) {
            const int k = t >> 2;
            const int j = t & 3;
            ws[VT_OFF + (size_t)k * 4096 + n0 + j] = sv[j][k];
        }
    }
}

// ---------------------------------------------------------------------------
// K2 (ROUND-8): per (m,p) block, S2 = sum_n w v v^T via u = sqrt(w) v, MFMA
// rank-reduction over n. u split hi/lo bf16 (RTZ).
// REVERTED: the R7 fused combine — its device-scope __threadfence() x1024
// blocks serialized L2 writebacks in the TCC (partial 163us, HBM 0.4%).
// NEW epilogue: G = Op^T Op is exactly symmetric, so tr(G(hl+hl^T)) =
// 2 tr(G hl): store P = hh + 2*hl in MFMA-native lane layout
//   record[q*256 + r*64 + lane]  (bank = lane&31 -> 2-way, free)
// -> the 16-way-conflict LDS transpose pass (2.8M conflict cycles in R7
// counters) is deleted. Also valid under any B-operand transpose ambiguity
// since tr(G X) = tr(G X^T) for symmetric G.
// NEW: zred/s1buf overlaid on swbuf (dead after main loop) -> LDS exactly
// 40,960 B -> 4 blocks/CU (grid is exactly 4x256: no dispatch tail).
// ---------------------------------------------------------------------------
__global__ __launch_bounds__(256, 4) void partial_kernel(const float* __restrict__ Wt,
                                                         const float* __restrict__ vT,
                                                         float* __restrict__ wsout) {
    const int m = blockIdx.x >> 2;
    const int p = blockIdx.x & 3;
    const int t = threadIdx.x;
    const int lane = t & 63;
    const int wv   = t >> 6;     // wave id 0..3

    __shared__ unsigned ubuf[4][2][32 * 36];  // [wave][hi/lo][k*36 + n/2] : 36,864 B
    __shared__ float swbuf[1024];             // sqrt(w); dead after main loop: 4,096 B
    float* const s1buf = swbuf;               // overlay [0..31]
    float* const zred  = swbuf + 32;          // overlay [32..39]

    // ---- stage w: sqrt, Z, count (swbuf region is wave-private: no barrier) ----
    const float4 wv4 = reinterpret_cast<const float4*>(Wt + (size_t)m * 4096 + p * 1024)[t];
    float zacc = wv4.x + wv4.y + wv4.z + wv4.w;
    float cacc = (wv4.x >= WEPS ? 1.f : 0.f) + (wv4.y >= WEPS ? 1.f : 0.f)
               + (wv4.z >= WEPS ? 1.f : 0.f) + (wv4.w >= WEPS ? 1.f : 0.f);
    reinterpret_cast<float4*>(swbuf)[t] =
        make_float4(sqrtf(wv4.x), sqrtf(wv4.y), sqrtf(wv4.z), sqrtf(wv4.w));

    f32x4 Chh[4], Chl[4];
    #pragma unroll
    for (int q = 0; q < 4; ++q) {
        Chh[q] = (f32x4){0.f, 0.f, 0.f, 0.f};
        Chl[q] = (f32x4){0.f, 0.f, 0.f, 0.f};
    }
    float s1acc[4] = {0.f, 0.f, 0.f, 0.f};

    const int krow = lane >> 3;        // 0..7
    const int nsub = (lane & 7) * 4;   // 0..28

    for (int rnd = 0; rnd < 4; ++rnd) {
        const int nloc0 = wv * 256 + rnd * 64;   // block-local n base of this wave-round

        // ---- conversion: 64 n x 32 k, fp32 -> u -> bf16 hi/lo in LDS ----
        #pragma unroll
        for (int it = 0; it < 8; ++it) {
            const int k  = krow + 8 * (it & 3);
            const int nn = nsub + 32 * (it >> 2);
            const float4 v4 = *reinterpret_cast<const float4*>(
                vT + (size_t)k * 4096 + p * 1024 + nloc0 + nn);
            const float4 s4 = *reinterpret_cast<const float4*>(&swbuf[nloc0 + nn]);
            const float ux = v4.x * s4.x, uy = v4.y * s4.y;
            const float uz = v4.z * s4.z, uw = v4.w * s4.w;
            const unsigned bx = __float_as_uint(ux), by = __float_as_uint(uy);
            const unsigned bz = __float_as_uint(uz), bw = __float_as_uint(uw);
            const unsigned hi01 = __builtin_amdgcn_perm(by, bx, 0x07060302u);
            const unsigned hi23 = __builtin_amdgcn_perm(bw, bz, 0x07060302u);
            const float lx = ux - __uint_as_float(bx & 0xFFFF0000u);
            const float ly = uy - __uint_as_float(by & 0xFFFF0000u);
            const float lz = uz - __uint_as_float(bz & 0xFFFF0000u);
            const float lw = uw - __uint_as_float(bw & 0xFFFF0000u);
            const unsigned lo01 = __builtin_amdgcn_perm(__float_as_uint(ly), __float_as_uint(lx), 0x07060302u);
            const unsigned lo23 = __builtin_amdgcn_perm(__float_as_uint(lw), __float_as_uint(lz), 0x07060302u);
            const int dwi = k * 36 + (nn >> 1);
            *reinterpret_cast<uint2*>(&ubuf[wv][0][dwi]) = make_uint2(hi01, hi23);
            *reinterpret_cast<uint2*>(&ubuf[wv][1][dwi]) = make_uint2(lo01, lo23);
            // S1 += w*v = sw*u
            s1acc[it & 3] += ux * s4.x + uy * s4.y + uz * s4.z + uw * s4.w;
        }

        // ---- MFMA: 2 chunks of 32 n ----
        #pragma unroll
        for (int c2 = 0; c2 < 2; ++c2) {
            const int ndw = (c2 * 32 + (lane >> 4) * 8) >> 1;
            const int r0 = (lane & 15) * 36 + ndw;
            const int r1 = r0 + 16 * 36;
            const short8 h0 = *reinterpret_cast<const short8*>(&ubuf[wv][0][r0]);
            const short8 h1 = *reinterpret_cast<const short8*>(&ubuf[wv][0][r1]);
            const short8 l0 = *reinterpret_cast<const short8*>(&ubuf[wv][1][r0]);
            const short8 l1 = *reinterpret_cast<const short8*>(&ubuf[wv][1][r1]);
            Chh[0] = __builtin_amdgcn_mfma_f32_16x16x32_bf16(h0, h0, Chh[0], 0, 0, 0);
            Chh[1] = __builtin_amdgcn_mfma_f32_16x16x32_bf16(h0, h1, Chh[1], 0, 0, 0);
            Chh[2] = __builtin_amdgcn_mfma_f32_16x16x32_bf16(h1, h0, Chh[2], 0, 0, 0);
            Chh[3] = __builtin_amdgcn_mfma_f32_16x16x32_bf16(h1, h1, Chh[3], 0, 0, 0);
            Chl[0] = __builtin_amdgcn_mfma_f32_16x16x32_bf16(h0, l0, Chl[0], 0, 0, 0);
            Chl[1] = __builtin_amdgcn_mfma_f32_16x16x32_bf16(h0, l1, Chl[1], 0, 0, 0);
            Chl[2] = __builtin_amdgcn_mfma_f32_16x16x32_bf16(h1, l0, Chl[2], 0, 0, 0);
            Chl[3] = __builtin_amdgcn_mfma_f32_16x16x32_bf16(h1, l1, Chl[3], 0, 0, 0);
        }
    }

    // ---- epilogue scatter: P = hh + 2*hl in MFMA-native lane layout ----
    // wave-private ubuf region; within-wave LDS ordering makes this safe
    // without a barrier (MFMA data-dep drained the reads).
    float* redw = reinterpret_cast<float*>(&ubuf[wv][0][0]);  // 1024 of 2304 dw
    #pragma unroll
    for (int q = 0; q < 4; ++q) {
        #pragma unroll
        for (int r = 0; r < 4; ++r) {
            redw[q * 256 + r * 64 + lane] = Chh[q][r] + 2.0f * Chl[q][r];
        }
    }

    // ---- wave-level Z/count reduce (registers, no LDS) ----
    #pragma unroll
    for (int s = 1; s < 64; s <<= 1) {
        zacc += __shfl_xor(zacc, s);
        cacc += __shfl_xor(cacc, s);
    }

    __syncthreads();   // B1: all conversions + scatters done; swbuf dead
    if (t < 32) s1buf[t] = 0.0f;
    if (lane == 0) { zred[wv] = zacc; zred[4 + wv] = cacc; }
    __syncthreads();   // B2: overlays initialized

    // ---- S1 reduce: 8 consecutive lanes share k ----
    #pragma unroll
    for (int j = 0; j < 4; ++j) {
        float r = s1acc[j];
        r += __shfl_xor(r, 1);
        r += __shfl_xor(r, 2);
        r += __shfl_xor(r, 4);
        if ((lane & 7) == 0) atomicAdd(&s1buf[krow + 8 * j], r);
    }
    __syncthreads();   // B3: s1 complete

    // ---- cross-wave sum + write record ----
    const size_t base = (size_t)(m * 4 + p) * PART_STRIDE;
    float o0 = 0.f, o1 = 0.f, o2 = 0.f, o3 = 0.f;
    #pragma unroll
    for (int ww = 0; ww < 4; ++ww) {
        const float4 x = *reinterpret_cast<const float4*>(
            &reinterpret_cast<float*>(&ubuf[ww][0][0])[t * 4]);
        o0 += x.x; o1 += x.y; o2 += x.z; o3 += x.w;
    }
    *reinterpret_cast<float4*>(&wsout[base + t * 4]) = make_float4(o0, o1, o2, o3);
    if (t == 0) wsout[base + 1056] = zred[0] + zred[1] + zred[2] + zred[3];
    if (t == 1) wsout[base + 1057] = zred[4] + zred[5] + zred[6] + zred[7];
    if (t < 32) wsout[base + 1024 + t] = s1buf[t];
}

// ---------------------------------------------------------------------------
// K3: combine (separate launch again — 2us beats 1024 device-scope fences).
//   G = op^T op ; psi = tr(G P)/Z - vbar^T G vbar ; gate count>=2
// Record P is in MFMA-native lane layout: element (a,b) lives at
//   ((a>>4)*2+(b>>4))*256 + (a&3)*64 + ((a>>2)&3)*16 + (b&15)
// Thread t wants (k, l0..l0+3), which is a contiguous aligned float4.
// ---------------------------------------------------------------------------
__global__ __launch_bounds__(256) void combine_kernel(const float* __restrict__ op,
                                                      const float* __restrict__ ws,
                                                      float* __restrict__ out) {
    const int m = blockIdx.x;
    const int t = threadIdx.x;

    __shared__ float omg[32 * 33];
    __shared__ float vbar[32];
    __shared__ float red[256];

    #pragma unroll
    for (int i = 0; i < 4; ++i) {
        const int g = t + 256 * i;
        omg[(g >> 5) * 33 + (g & 31)] = op[(size_t)m * 1024 + g];
    }

    const int k  = t >> 3;
    const int l0 = (t & 7) * 4;
    const int pbase = ((k >> 4) * 2 + (l0 >> 4)) * 256
                    + (k & 3) * 64 + ((k >> 2) & 3) * 16 + (l0 & 15);

    const size_t mb = (size_t)m * 4 * PART_STRIDE;
    float Z = 0.0f, cnt = 0.0f, s1 = 0.0f;
    float s2[4] = {0.f, 0.f, 0.f, 0.f};
    #pragma unroll
    for (int p2 = 0; p2 < 4; ++p2) {
        const size_t bp = mb + (size_t)p2 * PART_STRIDE;
        Z   += ws[bp + 1056];
        cnt += ws[bp + 1057];
        if (t < 32) s1 += ws[bp + 1024 + t];
        const float4 sp = *reinterpret_cast<const float4*>(&ws[bp + pbase]);
        s2[0] += sp.x; s2[1] += sp.y; s2[2] += sp.z; s2[3] += sp.w;
    }
    const float invZ = 1.0f / fmaxf(Z, 1e-30f);
    if (t < 32) vbar[t] = s1 * invZ;
    __syncthreads();

    float G[4] = {0.f, 0.f, 0.f, 0.f};
    #pragma unroll
    for (int i = 0; i < 32; ++i) {
        const float ok = omg[i * 33 + k];
        #pragma unroll
        for (int q = 0; q < 4; ++q) G[q] = fmaf(ok, omg[i * 33 + l0 + q], G[q]);
    }

    const float vk = vbar[k];
    float val = 0.0f;
    #pragma unroll
    for (int q = 0; q < 4; ++q)
        val += G[q] * (s2[q] * invZ - vk * vbar[l0 + q]);

    red[t] = val; __syncthreads();
    #pragma unroll
    for (int s = 128; s > 0; s >>= 1) {
        if (t < s) red[t] += red[t + s];
        __syncthreads();
    }
    if (t == 0) out[m] = (cnt >= 1.5f) ? red[0] : 0.0f;
}

// ---------------------------------------------------------------------------
extern "C" void kernel_launch(void* const* d_in, const int* in_sizes, int n_in,
                              void* d_out, int out_size, void* d_ws, size_t ws_size,
                              hipStream_t stream) {
    const float* W  = (const float*)d_in[0];  // (4096, 256)
    const float* mu = (const float*)d_in[1];  // (4096, 32)
    const float* oc = (const float*)d_in[2];  // (4096, 32, 32)
    const float* op = (const float*)d_in[3];  // (256, 32, 32)
    float* out = (float*)d_out;               // (256,)
    float* ws  = (float*)d_ws;

    prep_kernel<<<2048, 256, 0, stream>>>(W, mu, oc, ws);
    partial_kernel<<<1024, 256, 0, stream>>>(ws + WT_OFF, ws + VT_OFF, ws);
    combine_kernel<<<256, 256, 0, stream>>>(op, ws, out);
}